// Round 23
// baseline (241.613 us; speedup 1.0000x reference)
//
#include <hip/hip_runtime.h>
#include <math.h>

#define N_NODES 100000
#define N_EDGES 1600000
#define N_GRAPHS 256
#define IN_F 64
#define H_F 128
#define GN_EPS 1e-5f
#define PAD 32
#define NBINS 8
#define LCAP 512
#define BINCAP (1 << 18)
#define NSUB 16
#define SUBW 782
#define SBCAP 16384
#define MG 782             // mlp compute blocks
#define CPB 1612           // mlp riding-copy blocks
#define GCB 25000          // gather compute blocks
#define GCPB 1000          // gather riding-copy blocks
#define CP_EI4 800000      // ei int4 units
#define CP_EIB 825000      // + batch int4 units
#define EA_TOT4 3200000    // eattr float4 units
#define WIN_LO 800000      // fallback-path skip window (gsum/gsumq/wt) f4 units
#define WIN_HI 821504
#define BINB 512           // bin blocks inside fused binprep

typedef __attribute__((ext_vector_type(8))) short bf16x8;
typedef __attribute__((ext_vector_type(4))) float f32x4;

__device__ __forceinline__ float bf2f(unsigned short u) {
  return __uint_as_float(((unsigned int)u) << 16);
}
__device__ __forceinline__ unsigned short f2bf(float f) {
  unsigned int u = __float_as_uint(f);
  u += 0x7FFFu + ((u >> 16) & 1u);
  return (unsigned short)(u >> 16);
}
__device__ __forceinline__ int bsearch_batch(const int* __restrict__ batch, int target) {
  int lo = 0, hi = N_NODES;
  while (lo < hi) { int mid = (lo + hi) >> 1; if (batch[mid] < target) lo = mid + 1; else hi = mid; }
  return lo;
}

// ---- fused bin + prologue (cast x, transpose W, zero gsum, flat=-INF) ----
// Blocks [0, BINB): radix partition. Blocks >= BINB: prep segments.
// Counter block (ovfc/gbc/gbc2) is zeroed by hipMemsetAsync BEFORE this kernel.
#define PREP_XH   1600000
#define PREP_GS   (PREP_XH + 16384)
#define PREP_WT   (PREP_GS + 40960)
#define PREP_FL   (PREP_WT + 8192)
__global__ __launch_bounds__(256) void k_binprep(
    const int* __restrict__ src, const int* __restrict__ dst,
    unsigned int* __restrict__ binBuf, int* __restrict__ gbc,
    const float4* __restrict__ xin, const float* __restrict__ W1,
    const float* __restrict__ W2, const float* __restrict__ W3,
    ushort4* __restrict__ xh4, float4* __restrict__ gsum4,
    unsigned short* __restrict__ wt, float4* __restrict__ flat4) {
  const int t = threadIdx.x;
  if (blockIdx.x >= BINB) {                  // ---- prep blocks ----
    int i = (blockIdx.x - BINB) * 256 + t;
    if (i < PREP_XH) {
      float4 v = xin[i];
      ushort4 o;
      o.x = f2bf(v.x); o.y = f2bf(v.y); o.z = f2bf(v.z); o.w = f2bf(v.w);
      xh4[i] = o;
    } else if (i < PREP_GS) {
      gsum4[i - PREP_XH] = make_float4(0.f, 0.f, 0.f, 0.f);
    } else if (i < PREP_WT) {
      int j = i - PREP_GS;
      if (j < 8192) {
        int n = j >> 6, k = j & 63;
        wt[j] = f2bf(W1[(size_t)k * H_F + n]);
      } else if (j < 24576) {
        int jj = j - 8192;
        int n = jj >> 7, k = jj & 127;
        wt[j] = f2bf(W2[(size_t)k * H_F + n]);
      } else {
        int jj = j - 24576;
        int n = jj >> 7, k = jj & 127;
        wt[j] = f2bf(W3[(size_t)k * H_F + n]);
      }
    } else if (i < PREP_FL) {
      flat4[i - PREP_WT] = make_float4(-INFINITY, -INFINITY, -INFINITY, -INFINITY);
    }
    return;
  }
  // ---- bin blocks ----
  __shared__ unsigned int ebuf[NBINS][LCAP];
  __shared__ int lcnt[NBINS];
  __shared__ int lbase[NBINS];
  if (t < NBINS) lcnt[t] = 0;
  __syncthreads();
  for (int e0 = blockIdx.x * 256; e0 < N_EDGES; e0 += BINB * 256) {
    int e = e0 + t;
    if (e < N_EDGES) {
      int s = src[e], d = dst[e];
      int b = d / 12500;
      int p = atomicAdd(&lcnt[b], 1);
      ebuf[b][p] = ((unsigned)(d - b * 12500) << 17) | (unsigned)s;
    }
    __syncthreads();
    if (t < NBINS && lcnt[t] >= 256) lbase[t] = atomicAdd(&gbc[t], lcnt[t]);
    __syncthreads();
#pragma unroll
    for (int b = 0; b < NBINS; ++b) {
      int c = lcnt[b];
      if (c >= 256) {
        unsigned int* gp = binBuf + (size_t)b * BINCAP + lbase[b];
        for (int i = t; i < c; i += 256) gp[i] = ebuf[b][i];
      }
    }
    __syncthreads();
    if (t < NBINS && lcnt[t] >= 256) lcnt[t] = 0;
    __syncthreads();
  }
  if (t < NBINS && lcnt[t] > 0) lbase[t] = atomicAdd(&gbc[t], lcnt[t]);
  __syncthreads();
#pragma unroll
  for (int b = 0; b < NBINS; ++b) {
    int c = lcnt[b];
    if (c > 0) {
      unsigned int* gp = binBuf + (size_t)b * BINCAP + lbase[b];
      for (int i = t; i < c; i += 256) gp[i] = ebuf[b][i];
    }
  }
}

// ---- phase A2: split each parent bin into 16 sub-bins of 782 dsts ----
__global__ __launch_bounds__(256) void k_bin2(
    const unsigned int* __restrict__ binBuf, const int* __restrict__ gbc,
    unsigned int* __restrict__ binBuf2, int* __restrict__ gbc2) {
  __shared__ unsigned int ebuf[NSUB][LCAP];
  __shared__ int lcnt[NSUB];
  __shared__ int lbase[NSUB];
  const int t = threadIdx.x;
  const int p = blockIdx.x & 7;
  const int blk = blockIdx.x >> 3;
  const int nb = gbc[p];
  const unsigned int* buf = binBuf + (size_t)p * BINCAP;
  if (t < NSUB) lcnt[t] = 0;
  __syncthreads();
  for (int i0 = blk * 256; i0 < nb; i0 += 32 * 256) {
    int i = i0 + t;
    if (i < nb) {
      unsigned int e = buf[i];
      int dloc = (int)(e >> 17);
      int sub = dloc / SUBW;
      int p2 = atomicAdd(&lcnt[sub], 1);
      ebuf[sub][p2] = ((unsigned)(dloc - sub * SUBW) << 17) | (e & 131071u);
    }
    __syncthreads();
    if (t < NSUB && lcnt[t] >= 256)
      lbase[t] = atomicAdd(&gbc2[p * NSUB + t], lcnt[t]);
    __syncthreads();
#pragma unroll
    for (int b = 0; b < NSUB; ++b) {
      int c = lcnt[b];
      if (c >= 256) {
        unsigned int* gp = binBuf2 + (size_t)(p * NSUB + b) * SBCAP + lbase[b];
        for (int i2 = t; i2 < c; i2 += 256) gp[i2] = ebuf[b][i2];
      }
    }
    __syncthreads();
    if (t < NSUB && lcnt[t] >= 256) lcnt[t] = 0;
    __syncthreads();
  }
  if (t < NSUB && lcnt[t] > 0)
    lbase[t] = atomicAdd(&gbc2[p * NSUB + t], lcnt[t]);
  __syncthreads();
#pragma unroll
  for (int b = 0; b < NSUB; ++b) {
    int c = lcnt[b];
    if (c > 0) {
      unsigned int* gp = binBuf2 + (size_t)(p * NSUB + b) * SBCAP + lbase[b];
      for (int i2 = t; i2 < c; i2 += 256) gp[i2] = ebuf[b][i2];
    }
  }
}

// ---- phase B: per-sub-bin fill; csr assembled in LDS, dense copy-out ----
__global__ __launch_bounds__(256) void k_fill5(
    const unsigned int* __restrict__ binBuf2, const int* __restrict__ gbc2,
    int* __restrict__ csr, int* __restrict__ cnt,
    int* __restrict__ ovfc, int* __restrict__ ovf) {
  __shared__ int lcsr[SUBW * PAD];
  __shared__ int lcnt[SUBW];
  const int t = threadIdx.x;
  const int p = blockIdx.x & 7;
  const int sub = blockIdx.x >> 3;
  for (int j = t; j < SUBW; j += 256) lcnt[j] = 0;
  __syncthreads();
  const int n2 = gbc2[p * NSUB + sub];
  const unsigned int* buf = binBuf2 + (size_t)(p * NSUB + sub) * SBCAP;
  const int dbase = p * 12500 + sub * SUBW;
  for (int i = t; i < n2; i += 256) {
    unsigned int e = buf[i];
    int dloc2 = (int)(e >> 17);
    int s = (int)(e & 131071u);
    int pos = atomicAdd(&lcnt[dloc2], 1);
    if (pos < PAD) {
      lcsr[dloc2 * PAD + pos] = s;
    } else {
      int o = atomicAdd(ovfc, 1);
      ovf[2 * o] = s;
      ovf[2 * o + 1] = dbase + dloc2;
    }
  }
  __syncthreads();
  int rows = 12500 - sub * SUBW; if (rows > SUBW) rows = SUBW;
  int total4 = rows * (PAD / 4);
  int4* dst4 = (int4*)(csr + (size_t)dbase * PAD);
  const int4* src4 = (const int4*)lcsr;
  for (int i = t; i < total4; i += 256) dst4[i] = src4[i];
  for (int j = t; j < rows; j += 256)
    cnt[dbase + j] = lcnt[j];                 // raw count
}

// ---- gather (+optional riding ei/batch copy in blocks >= GCB) ----
__global__ __launch_bounds__(256) void k_gather(
    const unsigned short* __restrict__ xh, const int* __restrict__ csr,
    const int* __restrict__ cnt, unsigned short* __restrict__ xa,
    const int* __restrict__ ovfc, const int* __restrict__ ovf,
    const int4* __restrict__ ei4, const int4* __restrict__ bat4,
    float4* __restrict__ o_ei4, float4* __restrict__ o_b4) {
  if (blockIdx.x >= GCB) {                   // riding copy (primary path only)
    int cb = blockIdx.x - GCB;
    int stride = (gridDim.x - GCB) * 256;
    for (int i = cb * 256 + threadIdx.x; i < CP_EIB; i += stride) {
      if (i < CP_EI4) {
        int4 v = ei4[i];
        o_ei4[i] = make_float4((float)v.x, (float)v.y, (float)v.z, (float)v.w);
      } else {
        int j = i - CP_EI4;
        int4 v = bat4[j];
        o_b4[j] = make_float4((float)v.x, (float)v.y, (float)v.z, (float)v.w);
      }
    }
    return;
  }
  int wid = (blockIdx.x * 256 + threadIdx.x) >> 6;
  if (wid >= N_NODES) return;
  const int lane = threadIdx.x & 63;
  const int g = lane >> 4;
  const int fl = lane & 15;
  int rawdeg = cnt[wid];
  int deg = rawdeg > PAD ? PAD : rawdeg;
  int myE = csr[(size_t)wid * PAD + (lane & 31)];
  float s0 = 0.f, s1 = 0.f, s2 = 0.f, s3 = 0.f;
  int j = g;
  for (; j + 12 < deg; j += 16) {
    int sA = __shfl(myE, j);
    int sB = __shfl(myE, j + 4);
    int sC = __shfl(myE, j + 8);
    int sD = __shfl(myE, j + 12);
    ushort4 a = *(const ushort4*)&xh[(size_t)sA * IN_F + fl * 4];
    ushort4 b = *(const ushort4*)&xh[(size_t)sB * IN_F + fl * 4];
    ushort4 c = *(const ushort4*)&xh[(size_t)sC * IN_F + fl * 4];
    ushort4 d = *(const ushort4*)&xh[(size_t)sD * IN_F + fl * 4];
    s0 += bf2f(a.x) + bf2f(b.x) + bf2f(c.x) + bf2f(d.x);
    s1 += bf2f(a.y) + bf2f(b.y) + bf2f(c.y) + bf2f(d.y);
    s2 += bf2f(a.z) + bf2f(b.z) + bf2f(c.z) + bf2f(d.z);
    s3 += bf2f(a.w) + bf2f(b.w) + bf2f(c.w) + bf2f(d.w);
  }
  for (; j < deg; j += 4) {
    int sA = __shfl(myE, j);
    ushort4 a = *(const ushort4*)&xh[(size_t)sA * IN_F + fl * 4];
    s0 += bf2f(a.x); s1 += bf2f(a.y); s2 += bf2f(a.z); s3 += bf2f(a.w);
  }
  if (rawdeg > PAD && g == 0) {
    int n = *ovfc;
    for (int o = 0; o < n; ++o) {
      if (ovf[2 * o + 1] == wid) {
        int s = ovf[2 * o];
        ushort4 a = *(const ushort4*)&xh[(size_t)s * IN_F + fl * 4];
        s0 += bf2f(a.x); s1 += bf2f(a.y); s2 += bf2f(a.z); s3 += bf2f(a.w);
      }
    }
  }
  s0 += __shfl_xor(s0, 16); s1 += __shfl_xor(s1, 16);
  s2 += __shfl_xor(s2, 16); s3 += __shfl_xor(s3, 16);
  s0 += __shfl_xor(s0, 32); s1 += __shfl_xor(s1, 32);
  s2 += __shfl_xor(s2, 32); s3 += __shfl_xor(s3, 32);
  if (g == 0) {
    ushort4 self = *(const ushort4*)&xh[(size_t)wid * IN_F + fl * 4];
    s0 += bf2f(self.x); s1 += bf2f(self.y);
    s2 += bf2f(self.z); s3 += bf2f(self.w);
    ushort4 r;
    r.x = f2bf(s0); r.y = f2bf(s1); r.z = f2bf(s2); r.w = f2bf(s3);
    *(ushort4*)&xa[(size_t)wid * IN_F + fl * 4] = r;
  }
}

// ========== fused MLP (128-row, 512 thr) + riding copy; W2 reg-prefetch ==========
// eaMode=1: ride FULL eattr copy (gsum in d_ws). eaMode=0: ride ei+batch.
__global__ __launch_bounds__(512) void k_mlp(
    const unsigned short* __restrict__ xa,
    const unsigned short* __restrict__ wt1,
    const unsigned short* __restrict__ wt2,
    const unsigned short* __restrict__ wt3,
    const float* __restrict__ b1, const float* __restrict__ b2,
    const float* __restrict__ b3,
    unsigned short* __restrict__ h3,
    const int* __restrict__ batch,
    float* __restrict__ gsum, float* __restrict__ gsumq,
    const int4* __restrict__ ei4, const int4* __restrict__ bat4,
    const float4* __restrict__ ea4,
    float4* __restrict__ o_ei4, float4* __restrict__ o_b4,
    float4* __restrict__ o_ea4, int eaMode) {
  __shared__ unsigned short sh[128 * 128];   // 32 KB
  __shared__ float ssum[H_F], ssq[H_F];
  const int t = threadIdx.x;
  if (blockIdx.x >= MG) {                    // ---- riding copy blocks ----
    int cb = blockIdx.x - MG;
    if (eaMode) {
      for (int i = cb * 512 + t; i < EA_TOT4; i += CPB * 512)
        o_ea4[i] = ea4[i];
    } else {
      for (int i = cb * 512 + t; i < CP_EIB; i += CPB * 512) {
        if (i < CP_EI4) {
          int4 v = ei4[i];
          o_ei4[i] = make_float4((float)v.x, (float)v.y, (float)v.z, (float)v.w);
        } else {
          int j = i - CP_EI4;
          int4 v = bat4[j];
          o_b4[j] = make_float4((float)v.x, (float)v.y, (float)v.z, (float)v.w);
        }
      }
    }
    return;
  }
  const int lane = t & 63;
  const int wv = t >> 6;                     // 0..7
  const int row16 = lane & 15;
  const int kg = lane >> 4;
  const long blk0 = (long)blockIdx.x * 128;
  const int lr0 = (wv & 3) * 32;
  const int nb = (wv >> 2) * 4;
  f32x4 acc0[4], acc1[4];
  bf16x8 w2p[4][4];                          // W2 register prefetch

  // ---------- stage 1: K=64 from global xa, W1 (+W2 prefetch) ----------
  {
    long arow0 = blk0 + lr0 + row16;      if (arow0 > N_NODES - 1) arow0 = N_NODES - 1;
    long arow1 = blk0 + lr0 + 16 + row16; if (arow1 > N_NODES - 1) arow1 = N_NODES - 1;
    bf16x8 a0[2], a1[2];
    const unsigned short* ap0 = xa + arow0 * IN_F + kg * 8;
    const unsigned short* ap1 = xa + arow1 * IN_F + kg * 8;
#pragma unroll
    for (int s = 0; s < 2; ++s) {
      a0[s] = *(const bf16x8*)(ap0 + s * 32);
      a1[s] = *(const bf16x8*)(ap1 + s * 32);
    }
#pragma unroll
    for (int n = 0; n < 4; ++n) {            // prefetch W2 (hides post-barrier L2 latency)
      const unsigned short* wpn =
          wt2 + (size_t)((nb + n) * 16 + row16) * H_F + kg * 8;
#pragma unroll
      for (int s = 0; s < 4; ++s) w2p[n][s] = *(const bf16x8*)(wpn + s * 32);
    }
#pragma unroll
    for (int n = 0; n < 4; ++n) {
      acc0[n] = (f32x4){0.f, 0.f, 0.f, 0.f};
      acc1[n] = (f32x4){0.f, 0.f, 0.f, 0.f};
    }
#pragma unroll
    for (int n = 0; n < 4; ++n) {
      const unsigned short* wpn =
          wt1 + (size_t)((nb + n) * 16 + row16) * IN_F + kg * 8;
      bf16x8 b[2];
      b[0] = *(const bf16x8*)(wpn);
      b[1] = *(const bf16x8*)(wpn + 32);
      acc0[n] = __builtin_amdgcn_mfma_f32_16x16x32_bf16(a0[0], b[0], acc0[n], 0, 0, 0);
      acc0[n] = __builtin_amdgcn_mfma_f32_16x16x32_bf16(a0[1], b[1], acc0[n], 0, 0, 0);
      acc1[n] = __builtin_amdgcn_mfma_f32_16x16x32_bf16(a1[0], b[0], acc1[n], 0, 0, 0);
      acc1[n] = __builtin_amdgcn_mfma_f32_16x16x32_bf16(a1[1], b[1], acc1[n], 0, 0, 0);
    }
#pragma unroll
    for (int n = 0; n < 4; ++n) {
      int col = (nb + n) * 16 + row16;
      float bv = b1[col];
#pragma unroll
      for (int r = 0; r < 4; ++r) {
        int lrow0 = lr0 + kg * 4 + r;
        int lrow1 = lrow0 + 16;
        sh[lrow0 * 128 + (col ^ ((lrow0 & 7) << 3))] = f2bf(fmaxf(acc0[n][r] + bv, 0.f));
        sh[lrow1 * 128 + (col ^ ((lrow1 & 7) << 3))] = f2bf(fmaxf(acc1[n][r] + bv, 0.f));
      }
    }
  }
  __syncthreads();

  // ---------- stage 2: K=128 from LDS, W2 (prefetched) -> LDS ----------
  {
    const int lA0 = lr0 + row16, lA1 = lr0 + 16 + row16;
    bf16x8 a0[4], a1[4];
#pragma unroll
    for (int s = 0; s < 4; ++s) {
      int K0 = s * 32 + kg * 8;
      a0[s] = *(const bf16x8*)&sh[lA0 * 128 + (K0 ^ ((lA0 & 7) << 3))];
      a1[s] = *(const bf16x8*)&sh[lA1 * 128 + (K0 ^ ((lA1 & 7) << 3))];
    }
#pragma unroll
    for (int n = 0; n < 4; ++n) {
      acc0[n] = (f32x4){0.f, 0.f, 0.f, 0.f};
      acc1[n] = (f32x4){0.f, 0.f, 0.f, 0.f};
    }
#pragma unroll
    for (int n = 0; n < 4; ++n) {
#pragma unroll
      for (int s = 0; s < 4; ++s) {
        acc0[n] = __builtin_amdgcn_mfma_f32_16x16x32_bf16(a0[s], w2p[n][s], acc0[n], 0, 0, 0);
        acc1[n] = __builtin_amdgcn_mfma_f32_16x16x32_bf16(a1[s], w2p[n][s], acc1[n], 0, 0, 0);
      }
    }
    __syncthreads();
#pragma unroll
    for (int n = 0; n < 4; ++n) {
      int col = (nb + n) * 16 + row16;
      float bv = b2[col];
#pragma unroll
      for (int r = 0; r < 4; ++r) {
        int lrow0 = lr0 + kg * 4 + r;
        int lrow1 = lrow0 + 16;
        sh[lrow0 * 128 + (col ^ ((lrow0 & 7) << 3))] = f2bf(fmaxf(acc0[n][r] + bv, 0.f));
        sh[lrow1 * 128 + (col ^ ((lrow1 & 7) << 3))] = f2bf(fmaxf(acc1[n][r] + bv, 0.f));
      }
    }
  }
  __syncthreads();

  // ---------- stage 3: K=128 from LDS, W3 -> global h3 + stats ----------
  {
    const int lA0 = lr0 + row16, lA1 = lr0 + 16 + row16;
    bf16x8 a0[4], a1[4];
#pragma unroll
    for (int s = 0; s < 4; ++s) {
      int K0 = s * 32 + kg * 8;
      a0[s] = *(const bf16x8*)&sh[lA0 * 128 + (K0 ^ ((lA0 & 7) << 3))];
      a1[s] = *(const bf16x8*)&sh[lA1 * 128 + (K0 ^ ((lA1 & 7) << 3))];
    }
#pragma unroll
    for (int n = 0; n < 4; ++n) {
      acc0[n] = (f32x4){0.f, 0.f, 0.f, 0.f};
      acc1[n] = (f32x4){0.f, 0.f, 0.f, 0.f};
    }
#pragma unroll
    for (int n = 0; n < 4; ++n) {
      const unsigned short* wpn =
          wt3 + (size_t)((nb + n) * 16 + row16) * H_F + kg * 8;
      bf16x8 b[4];
#pragma unroll
      for (int s = 0; s < 4; ++s) b[s] = *(const bf16x8*)(wpn + s * 32);
#pragma unroll
      for (int s = 0; s < 4; ++s) {
        acc0[n] = __builtin_amdgcn_mfma_f32_16x16x32_bf16(a0[s], b[s], acc0[n], 0, 0, 0);
        acc1[n] = __builtin_amdgcn_mfma_f32_16x16x32_bf16(a1[s], b[s], acc1[n], 0, 0, 0);
      }
    }
#pragma unroll
    for (int n = 0; n < 4; ++n) {
      int col = (nb + n) * 16 + row16;
      float bv = b3[col];
#pragma unroll
      for (int r = 0; r < 4; ++r) {
        long row0 = blk0 + lr0 + kg * 4 + r;
        long row1 = row0 + 16;
        if (row0 < N_NODES)
          h3[row0 * H_F + col] = f2bf(fmaxf(acc0[n][r] + bv, 0.f));
        if (row1 < N_NODES)
          h3[row1 * H_F + col] = f2bf(fmaxf(acc1[n][r] + bv, 0.f));
      }
    }
    long lastrow = blk0 + 127; if (lastrow > N_NODES - 1) lastrow = N_NODES - 1;
    const int glo = batch[blk0];
    const int ghi = batch[lastrow];
    int br0[4], br1[4];
#pragma unroll
    for (int r = 0; r < 4; ++r) {
      long row0 = blk0 + lr0 + kg * 4 + r;
      long row1 = row0 + 16;
      br0[r] = (row0 < N_NODES) ? batch[row0] : -1;
      br1[r] = (row1 < N_NODES) ? batch[row1] : -1;
    }
    for (int g = glo; g <= ghi; ++g) {
      if (t < H_F) { ssum[t] = 0.f; ssq[t] = 0.f; }
      __syncthreads();
#pragma unroll
      for (int n = 0; n < 4; ++n) {
        int col = (nb + n) * 16 + row16;
        float bvn = b3[col];
        float sn = 0.f, qn = 0.f;
#pragma unroll
        for (int r = 0; r < 4; ++r) {
          if (br0[r] == g) { float f = fmaxf(acc0[n][r] + bvn, 0.f); sn += f; qn += f * f; }
          if (br1[r] == g) { float f = fmaxf(acc1[n][r] + bvn, 0.f); sn += f; qn += f * f; }
        }
        sn += __shfl_xor(sn, 16); qn += __shfl_xor(qn, 16);
        sn += __shfl_xor(sn, 32); qn += __shfl_xor(qn, 32);
        if (kg == 0) {
          atomicAdd(&ssum[col], sn);
          atomicAdd(&ssq[col], qn);
        }
      }
      __syncthreads();
      if (t < H_F) {
        unsafeAtomicAdd(&gsum[(size_t)g * H_F + t], ssum[t]);
        unsafeAtomicAdd(&gsumq[(size_t)g * H_F + t], ssq[t]);
      }
      __syncthreads();
    }
  }
}

// ---- apply2: inline finalize; h3 bf16 -> hemb fp32 + flat segment max ----
__global__ __launch_bounds__(256) void k_apply2(
    const unsigned short* __restrict__ h3, const int* __restrict__ batch,
    const float* __restrict__ gsum, const float* __restrict__ gsumsq,
    const float* __restrict__ gms, const float* __restrict__ gw,
    const float* __restrict__ gb, float* __restrict__ hemb,
    float* __restrict__ flat) {
  const int t = threadIdx.x;
  const int rg = t >> 5, fq = t & 31;
  const int m0 = blockIdx.x * 32;
  const int r0 = m0 + rg * 4;
  const int c0 = fq * 4;
  const float4 bb = *(const float4*)&gb[c0];
  const float4 gm = *(const float4*)&gms[c0];
  const float4 gwv = *(const float4*)&gw[c0];
  const int glo = batch[m0], ghi = batch[m0 + 31];
  __shared__ int sb[2];
  __shared__ __align__(16) float4 mred[8][32];
  if (glo == ghi) {
    if (t < 2) sb[t] = bsearch_batch(batch, glo + t);
    __syncthreads();
    float c = fmaxf((float)(sb[1] - sb[0]), 1.0f);
    float4 S = *(const float4*)&gsum[(size_t)glo * H_F + c0];
    float4 Q = *(const float4*)&gsumsq[(size_t)glo * H_F + c0];
    float4 mm, ss;
    {
      float mean, ms, var;
      mean = S.x / c; ms = mean * gm.x; var = fmaxf(Q.x / c - 2.f * ms * mean + ms * ms, 0.f);
      mm.x = ms; ss.x = gwv.x * rsqrtf(var + GN_EPS);
      mean = S.y / c; ms = mean * gm.y; var = fmaxf(Q.y / c - 2.f * ms * mean + ms * ms, 0.f);
      mm.y = ms; ss.y = gwv.y * rsqrtf(var + GN_EPS);
      mean = S.z / c; ms = mean * gm.z; var = fmaxf(Q.z / c - 2.f * ms * mean + ms * ms, 0.f);
      mm.z = ms; ss.z = gwv.z * rsqrtf(var + GN_EPS);
      mean = S.w / c; ms = mean * gm.w; var = fmaxf(Q.w / c - 2.f * ms * mean + ms * ms, 0.f);
      mm.w = ms; ss.w = gwv.w * rsqrtf(var + GN_EPS);
    }
    float4 mx = {-INFINITY, -INFINITY, -INFINITY, -INFINITY};
#pragma unroll
    for (int i = 0; i < 4; ++i) {
      size_t idx = (size_t)(r0 + i) * H_F + c0;
      ushort4 u = *(const ushort4*)&h3[idx];
      float4 v;
      v.x = fmaxf((bf2f(u.x) - mm.x) * ss.x + bb.x, 0.f);
      v.y = fmaxf((bf2f(u.y) - mm.y) * ss.y + bb.y, 0.f);
      v.z = fmaxf((bf2f(u.z) - mm.z) * ss.z + bb.z, 0.f);
      v.w = fmaxf((bf2f(u.w) - mm.w) * ss.w + bb.w, 0.f);
      *(float4*)&hemb[idx] = v;
      mx.x = fmaxf(mx.x, v.x); mx.y = fmaxf(mx.y, v.y);
      mx.z = fmaxf(mx.z, v.z); mx.w = fmaxf(mx.w, v.w);
    }
    mred[rg][fq] = mx;
    __syncthreads();
    if (rg == 0) {
#pragma unroll
      for (int j = 1; j < 8; ++j) {
        float4 a = mred[j][fq];
        mx.x = fmaxf(mx.x, a.x); mx.y = fmaxf(mx.y, a.y);
        mx.z = fmaxf(mx.z, a.z); mx.w = fmaxf(mx.w, a.w);
      }
      int* pf = (int*)&flat[(size_t)glo * H_F + c0];
      atomicMax(pf + 0, __float_as_int(mx.x));
      atomicMax(pf + 1, __float_as_int(mx.y));
      atomicMax(pf + 2, __float_as_int(mx.z));
      atomicMax(pf + 3, __float_as_int(mx.w));
    }
  } else {
    int gcur = -1;
    float4 mm = {0,0,0,0}, ss = {0,0,0,0};
    float4 mx = {-INFINITY, -INFINITY, -INFINITY, -INFINITY};
#pragma unroll
    for (int i = 0; i < 4; ++i) {
      int g = batch[r0 + i];
      if (g != gcur) {
        if (gcur >= 0) {
          int* pf = (int*)&flat[(size_t)gcur * H_F + c0];
          atomicMax(pf + 0, __float_as_int(mx.x));
          atomicMax(pf + 1, __float_as_int(mx.y));
          atomicMax(pf + 2, __float_as_int(mx.z));
          atomicMax(pf + 3, __float_as_int(mx.w));
          mx = make_float4(-INFINITY, -INFINITY, -INFINITY, -INFINITY);
        }
        gcur = g;
        int lo = bsearch_batch(batch, g);
        int hi = bsearch_batch(batch, g + 1);
        float c = fmaxf((float)(hi - lo), 1.0f);
        float4 S = *(const float4*)&gsum[(size_t)g * H_F + c0];
        float4 Q = *(const float4*)&gsumsq[(size_t)g * H_F + c0];
        float mean, ms, var;
        mean = S.x / c; ms = mean * gm.x; var = fmaxf(Q.x / c - 2.f * ms * mean + ms * ms, 0.f);
        mm.x = ms; ss.x = gwv.x * rsqrtf(var + GN_EPS);
        mean = S.y / c; ms = mean * gm.y; var = fmaxf(Q.y / c - 2.f * ms * mean + ms * ms, 0.f);
        mm.y = ms; ss.y = gwv.y * rsqrtf(var + GN_EPS);
        mean = S.z / c; ms = mean * gm.z; var = fmaxf(Q.z / c - 2.f * ms * mean + ms * ms, 0.f);
        mm.z = ms; ss.z = gwv.z * rsqrtf(var + GN_EPS);
        mean = S.w / c; ms = mean * gm.w; var = fmaxf(Q.w / c - 2.f * ms * mean + ms * ms, 0.f);
        mm.w = ms; ss.w = gwv.w * rsqrtf(var + GN_EPS);
      }
      size_t idx = (size_t)(r0 + i) * H_F + c0;
      ushort4 u = *(const ushort4*)&h3[idx];
      float4 v;
      v.x = fmaxf((bf2f(u.x) - mm.x) * ss.x + bb.x, 0.f);
      v.y = fmaxf((bf2f(u.y) - mm.y) * ss.y + bb.y, 0.f);
      v.z = fmaxf((bf2f(u.z) - mm.z) * ss.z + bb.z, 0.f);
      v.w = fmaxf((bf2f(u.w) - mm.w) * ss.w + bb.w, 0.f);
      *(float4*)&hemb[idx] = v;
      mx.x = fmaxf(mx.x, v.x); mx.y = fmaxf(mx.y, v.y);
      mx.z = fmaxf(mx.z, v.z); mx.w = fmaxf(mx.w, v.w);
    }
    int* pf = (int*)&flat[(size_t)gcur * H_F + c0];
    atomicMax(pf + 0, __float_as_int(mx.x));
    atomicMax(pf + 1, __float_as_int(mx.y));
    atomicMax(pf + 2, __float_as_int(mx.z));
    atomicMax(pf + 3, __float_as_int(mx.w));
  }
}

// ---- fallback tail copy (small-ws path only) ----
__global__ __launch_bounds__(256) void k_copy_ea(
    const float4* __restrict__ ea4, float4* __restrict__ o_ea4, int n4) {
  int i = blockIdx.x * 256 + threadIdx.x;
  if (i < n4) o_ea4[i] = ea4[i];
}

extern "C" void kernel_launch(void* const* d_in, const int* in_sizes, int n_in,
                              void* d_out, int out_size, void* d_ws, size_t ws_size,
                              hipStream_t stream) {
  const float* inputs = (const float*)d_in[0];
  const int*   ei     = (const int*)d_in[1];
  const int*   batch  = (const int*)d_in[2];
  const float* eattr  = (const float*)d_in[3];
  const float* W1 = (const float*)d_in[4];
  const float* b1 = (const float*)d_in[5];
  const float* W2 = (const float*)d_in[6];
  const float* b2 = (const float*)d_in[7];
  const float* W3 = (const float*)d_in[8];
  const float* b3 = (const float*)d_in[9];
  const float* gw  = (const float*)d_in[10];
  const float* gb  = (const float*)d_in[11];
  const float* gms = (const float*)d_in[12];

  float* out = (float*)d_out;
  float* hemb  = out;
  float* flat  = out + 12800000;
  float* o_ei  = out + 12832768;
  float* o_ea  = out + 16032768;
  float* o_b   = out + 28832768;

  unsigned int*   binBuf  = (unsigned int*)hemb;
  unsigned int*   binBuf2 = (unsigned int*)(hemb + 2100000);
  unsigned short* xh = (unsigned short*)(hemb + 4200000);
  unsigned short* xa = (unsigned short*)(hemb + 7600000);
  int*            csr = (int*)o_ea;

  // big path: h3 + gsum/gsumq/wt all in d_ws (needs >= 25,944,064 B)
  const bool big = ws_size >= (size_t)25944064;
  unsigned short* h3;
  float *gsum, *gsumq;
  unsigned short *wt;
  int *cnt, *ovfc, *gbc, *gbc2, *ovf;
  if (big) {
    float* ws = (float*)d_ws;
    h3    = (unsigned short*)d_ws;            // 6.4M floats
    gsum  = ws + 6400000;
    gsumq = ws + 6432768;
    wt    = (unsigned short*)(ws + 6465536);
    cnt   = (int*)o_ea + 3400000;             // o_ea hole; dead before mlp ride
    ovfc  = (int*)o_ea + 3500000;
  } else {
    h3    = (unsigned short*)(o_ea + 6400000);
    gsum  = o_ea + 3200000;                   // window (fallback skips it? no:
    gsumq = o_ea + 3232768;                   //  fallback rides ei+batch, o_ea
    wt    = (unsigned short*)(o_ea + 3265536);//  written only by k_copy_ea last)
    cnt   = (int*)o_ei;
    ovfc  = (int*)o_ei + 100000;
  }
  gbc  = ovfc + 8;
  gbc2 = ovfc + 16;
  ovf  = ovfc + 160;
  unsigned short* wt1 = wt;
  unsigned short* wt2 = wt + 8192;
  unsigned short* wt3 = wt + 24576;

  hipMemsetAsync(ovfc, 0, 160 * sizeof(int), stream);   // ovfc+gbc+gbc2
  const int prepBlocks = (PREP_FL + 255) / 256;         // 6506
  k_binprep<<<BINB + prepBlocks, 256, 0, stream>>>(
      ei, ei + N_EDGES, binBuf, gbc, (const float4*)inputs, W1, W2, W3,
      (ushort4*)xh, (float4*)gsum, wt, (float4*)flat);
  k_bin2<<<256, 256, 0, stream>>>(binBuf, gbc, binBuf2, gbc2);
  k_fill5<<<NBINS * NSUB, 256, 0, stream>>>(binBuf2, gbc2, csr, cnt, ovfc, ovf);
  if (big) {
    k_gather<<<GCB + GCPB, 256, 0, stream>>>(xh, csr, cnt, xa, ovfc, ovf,
        (const int4*)ei, (const int4*)batch, (float4*)o_ei, (float4*)o_b);
    k_mlp<<<MG + CPB, 512, 0, stream>>>(xa, wt1, wt2, wt3, b1, b2, b3, h3, batch,
        gsum, gsumq, (const int4*)ei, (const int4*)batch, (const float4*)eattr,
        (float4*)o_ei, (float4*)o_b, (float4*)o_ea, 1);
    k_apply2<<<N_NODES / 32, 256, 0, stream>>>(h3, batch, gsum, gsumq, gms, gw, gb,
                                               hemb, flat);
  } else {
    k_gather<<<GCB, 256, 0, stream>>>(xh, csr, cnt, xa, ovfc, ovf,
        (const int4*)ei, (const int4*)batch, (float4*)o_ei, (float4*)o_b);
    k_mlp<<<MG + CPB, 512, 0, stream>>>(xa, wt1, wt2, wt3, b1, b2, b3, h3, batch,
        gsum, gsumq, (const int4*)ei, (const int4*)batch, (const float4*)eattr,
        (float4*)o_ei, (float4*)o_b, (float4*)o_ea, 0);
    k_apply2<<<N_NODES / 32, 256, 0, stream>>>(h3, batch, gsum, gsumq, gms, gw, gb,
                                               hemb, flat);
    k_copy_ea<<<(N_EDGES * 2 + 255) / 256, 256, 0, stream>>>(
        (const float4*)eattr, (float4*)o_ea, N_EDGES * 2);
  }
}

// Round 24
// 231.952 us; speedup vs baseline: 1.0417x; 1.0417x over previous
//
#include <hip/hip_runtime.h>
#include <math.h>

#define N_NODES 100000
#define N_EDGES 1600000
#define N_GRAPHS 256
#define IN_F 64
#define H_F 128
#define GN_EPS 1e-5f
#define PAD 32
#define NBINS 8
#define LCAP 512
#define BINCAP (1 << 18)
#define NSUB 16
#define SUBW 782
#define SBCAP 16384
#define MG 782             // mlp compute blocks
#define CPB 1612           // mlp riding-copy blocks
#define GCB 25000          // gather compute blocks
#define GCPB 1000          // gather riding-copy blocks
#define CP_EI4 800000      // ei int4 units
#define CP_EIB 825000      // + batch int4 units
#define EA_TOT4 3200000    // eattr float4 units
#define BINB 512           // bin blocks inside fused binprep

typedef __attribute__((ext_vector_type(8))) short bf16x8;
typedef __attribute__((ext_vector_type(4))) float f32x4;

__device__ __forceinline__ float bf2f(unsigned short u) {
  return __uint_as_float(((unsigned int)u) << 16);
}
__device__ __forceinline__ unsigned short f2bf(float f) {
  unsigned int u = __float_as_uint(f);
  u += 0x7FFFu + ((u >> 16) & 1u);
  return (unsigned short)(u >> 16);
}
__device__ __forceinline__ int bsearch_batch(const int* __restrict__ batch, int target) {
  int lo = 0, hi = N_NODES;
  while (lo < hi) { int mid = (lo + hi) >> 1; if (batch[mid] < target) lo = mid + 1; else hi = mid; }
  return lo;
}

// ---- fused bin + prologue (cast x, transpose W, zero gsum, flat=-INF) ----
#define PREP_XH   1600000
#define PREP_GS   (PREP_XH + 16384)
#define PREP_WT   (PREP_GS + 40960)
#define PREP_FL   (PREP_WT + 8192)
__global__ __launch_bounds__(256) void k_binprep(
    const int* __restrict__ src, const int* __restrict__ dst,
    unsigned int* __restrict__ binBuf, int* __restrict__ gbc,
    const float4* __restrict__ xin, const float* __restrict__ W1,
    const float* __restrict__ W2, const float* __restrict__ W3,
    ushort4* __restrict__ xh4, float4* __restrict__ gsum4,
    unsigned short* __restrict__ wt, float4* __restrict__ flat4) {
  const int t = threadIdx.x;
  if (blockIdx.x >= BINB) {                  // ---- prep blocks ----
    int i = (blockIdx.x - BINB) * 256 + t;
    if (i < PREP_XH) {
      float4 v = xin[i];
      ushort4 o;
      o.x = f2bf(v.x); o.y = f2bf(v.y); o.z = f2bf(v.z); o.w = f2bf(v.w);
      xh4[i] = o;
    } else if (i < PREP_GS) {
      gsum4[i - PREP_XH] = make_float4(0.f, 0.f, 0.f, 0.f);
    } else if (i < PREP_WT) {
      int j = i - PREP_GS;
      if (j < 8192) {
        int n = j >> 6, k = j & 63;
        wt[j] = f2bf(W1[(size_t)k * H_F + n]);
      } else if (j < 24576) {
        int jj = j - 8192;
        int n = jj >> 7, k = jj & 127;
        wt[j] = f2bf(W2[(size_t)k * H_F + n]);
      } else {
        int jj = j - 24576;
        int n = jj >> 7, k = jj & 127;
        wt[j] = f2bf(W3[(size_t)k * H_F + n]);
      }
    } else if (i < PREP_FL) {
      flat4[i - PREP_WT] = make_float4(-INFINITY, -INFINITY, -INFINITY, -INFINITY);
    }
    return;
  }
  // ---- bin blocks ----
  __shared__ unsigned int ebuf[NBINS][LCAP];
  __shared__ int lcnt[NBINS];
  __shared__ int lbase[NBINS];
  if (t < NBINS) lcnt[t] = 0;
  __syncthreads();
  for (int e0 = blockIdx.x * 256; e0 < N_EDGES; e0 += BINB * 256) {
    int e = e0 + t;
    if (e < N_EDGES) {
      int s = src[e], d = dst[e];
      int b = d / 12500;
      int p = atomicAdd(&lcnt[b], 1);
      ebuf[b][p] = ((unsigned)(d - b * 12500) << 17) | (unsigned)s;
    }
    __syncthreads();
    if (t < NBINS && lcnt[t] >= 256) lbase[t] = atomicAdd(&gbc[t], lcnt[t]);
    __syncthreads();
#pragma unroll
    for (int b = 0; b < NBINS; ++b) {
      int c = lcnt[b];
      if (c >= 256) {
        unsigned int* gp = binBuf + (size_t)b * BINCAP + lbase[b];
        for (int i = t; i < c; i += 256) gp[i] = ebuf[b][i];
      }
    }
    __syncthreads();
    if (t < NBINS && lcnt[t] >= 256) lcnt[t] = 0;
    __syncthreads();
  }
  if (t < NBINS && lcnt[t] > 0) lbase[t] = atomicAdd(&gbc[t], lcnt[t]);
  __syncthreads();
#pragma unroll
  for (int b = 0; b < NBINS; ++b) {
    int c = lcnt[b];
    if (c > 0) {
      unsigned int* gp = binBuf + (size_t)b * BINCAP + lbase[b];
      for (int i = t; i < c; i += 256) gp[i] = ebuf[b][i];
    }
  }
}

// ---- phase A2: split each parent bin into 16 sub-bins of 782 dsts ----
__global__ __launch_bounds__(256) void k_bin2(
    const unsigned int* __restrict__ binBuf, const int* __restrict__ gbc,
    unsigned int* __restrict__ binBuf2, int* __restrict__ gbc2) {
  __shared__ unsigned int ebuf[NSUB][LCAP];
  __shared__ int lcnt[NSUB];
  __shared__ int lbase[NSUB];
  const int t = threadIdx.x;
  const int p = blockIdx.x & 7;
  const int blk = blockIdx.x >> 3;
  const int nb = gbc[p];
  const unsigned int* buf = binBuf + (size_t)p * BINCAP;
  if (t < NSUB) lcnt[t] = 0;
  __syncthreads();
  for (int i0 = blk * 256; i0 < nb; i0 += 32 * 256) {
    int i = i0 + t;
    if (i < nb) {
      unsigned int e = buf[i];
      int dloc = (int)(e >> 17);
      int sub = dloc / SUBW;
      int p2 = atomicAdd(&lcnt[sub], 1);
      ebuf[sub][p2] = ((unsigned)(dloc - sub * SUBW) << 17) | (e & 131071u);
    }
    __syncthreads();
    if (t < NSUB && lcnt[t] >= 256)
      lbase[t] = atomicAdd(&gbc2[p * NSUB + t], lcnt[t]);
    __syncthreads();
#pragma unroll
    for (int b = 0; b < NSUB; ++b) {
      int c = lcnt[b];
      if (c >= 256) {
        unsigned int* gp = binBuf2 + (size_t)(p * NSUB + b) * SBCAP + lbase[b];
        for (int i2 = t; i2 < c; i2 += 256) gp[i2] = ebuf[b][i2];
      }
    }
    __syncthreads();
    if (t < NSUB && lcnt[t] >= 256) lcnt[t] = 0;
    __syncthreads();
  }
  if (t < NSUB && lcnt[t] > 0)
    lbase[t] = atomicAdd(&gbc2[p * NSUB + t], lcnt[t]);
  __syncthreads();
#pragma unroll
  for (int b = 0; b < NSUB; ++b) {
    int c = lcnt[b];
    if (c > 0) {
      unsigned int* gp = binBuf2 + (size_t)(p * NSUB + b) * SBCAP + lbase[b];
      for (int i2 = t; i2 < c; i2 += 256) gp[i2] = ebuf[b][i2];
    }
  }
}

// ---- phase B: per-sub-bin fill; csr assembled in LDS, dense copy-out ----
__global__ __launch_bounds__(256) void k_fill5(
    const unsigned int* __restrict__ binBuf2, const int* __restrict__ gbc2,
    int* __restrict__ csr, int* __restrict__ cnt,
    int* __restrict__ ovfc, int* __restrict__ ovf) {
  __shared__ int lcsr[SUBW * PAD];
  __shared__ int lcnt[SUBW];
  const int t = threadIdx.x;
  const int p = blockIdx.x & 7;
  const int sub = blockIdx.x >> 3;
  for (int j = t; j < SUBW; j += 256) lcnt[j] = 0;
  __syncthreads();
  const int n2 = gbc2[p * NSUB + sub];
  const unsigned int* buf = binBuf2 + (size_t)(p * NSUB + sub) * SBCAP;
  const int dbase = p * 12500 + sub * SUBW;
  for (int i = t; i < n2; i += 256) {
    unsigned int e = buf[i];
    int dloc2 = (int)(e >> 17);
    int s = (int)(e & 131071u);
    int pos = atomicAdd(&lcnt[dloc2], 1);
    if (pos < PAD) {
      lcsr[dloc2 * PAD + pos] = s;
    } else {
      int o = atomicAdd(ovfc, 1);
      ovf[2 * o] = s;
      ovf[2 * o + 1] = dbase + dloc2;
    }
  }
  __syncthreads();
  int rows = 12500 - sub * SUBW; if (rows > SUBW) rows = SUBW;
  int total4 = rows * (PAD / 4);
  int4* dst4 = (int4*)(csr + (size_t)dbase * PAD);
  const int4* src4 = (const int4*)lcsr;
  for (int i = t; i < total4; i += 256) dst4[i] = src4[i];
  for (int j = t; j < rows; j += 256)
    cnt[dbase + j] = lcnt[j];                 // raw count
}

// ---- gather (+riding ei/batch copy in blocks >= GCB on big path) ----
__global__ __launch_bounds__(256) void k_gather(
    const unsigned short* __restrict__ xh, const int* __restrict__ csr,
    const int* __restrict__ cnt, unsigned short* __restrict__ xa,
    const int* __restrict__ ovfc, const int* __restrict__ ovf,
    const int4* __restrict__ ei4, const int4* __restrict__ bat4,
    float4* __restrict__ o_ei4, float4* __restrict__ o_b4) {
  if (blockIdx.x >= GCB) {
    int cb = blockIdx.x - GCB;
    int stride = (gridDim.x - GCB) * 256;
    for (int i = cb * 256 + threadIdx.x; i < CP_EIB; i += stride) {
      if (i < CP_EI4) {
        int4 v = ei4[i];
        o_ei4[i] = make_float4((float)v.x, (float)v.y, (float)v.z, (float)v.w);
      } else {
        int j = i - CP_EI4;
        int4 v = bat4[j];
        o_b4[j] = make_float4((float)v.x, (float)v.y, (float)v.z, (float)v.w);
      }
    }
    return;
  }
  int wid = (blockIdx.x * 256 + threadIdx.x) >> 6;
  if (wid >= N_NODES) return;
  const int lane = threadIdx.x & 63;
  const int g = lane >> 4;
  const int fl = lane & 15;
  int rawdeg = cnt[wid];
  int deg = rawdeg > PAD ? PAD : rawdeg;
  int myE = csr[(size_t)wid * PAD + (lane & 31)];
  float s0 = 0.f, s1 = 0.f, s2 = 0.f, s3 = 0.f;
  int j = g;
  for (; j + 12 < deg; j += 16) {
    int sA = __shfl(myE, j);
    int sB = __shfl(myE, j + 4);
    int sC = __shfl(myE, j + 8);
    int sD = __shfl(myE, j + 12);
    ushort4 a = *(const ushort4*)&xh[(size_t)sA * IN_F + fl * 4];
    ushort4 b = *(const ushort4*)&xh[(size_t)sB * IN_F + fl * 4];
    ushort4 c = *(const ushort4*)&xh[(size_t)sC * IN_F + fl * 4];
    ushort4 d = *(const ushort4*)&xh[(size_t)sD * IN_F + fl * 4];
    s0 += bf2f(a.x) + bf2f(b.x) + bf2f(c.x) + bf2f(d.x);
    s1 += bf2f(a.y) + bf2f(b.y) + bf2f(c.y) + bf2f(d.y);
    s2 += bf2f(a.z) + bf2f(b.z) + bf2f(c.z) + bf2f(d.z);
    s3 += bf2f(a.w) + bf2f(b.w) + bf2f(c.w) + bf2f(d.w);
  }
  for (; j < deg; j += 4) {
    int sA = __shfl(myE, j);
    ushort4 a = *(const ushort4*)&xh[(size_t)sA * IN_F + fl * 4];
    s0 += bf2f(a.x); s1 += bf2f(a.y); s2 += bf2f(a.z); s3 += bf2f(a.w);
  }
  if (rawdeg > PAD && g == 0) {
    int n = *ovfc;
    for (int o = 0; o < n; ++o) {
      if (ovf[2 * o + 1] == wid) {
        int s = ovf[2 * o];
        ushort4 a = *(const ushort4*)&xh[(size_t)s * IN_F + fl * 4];
        s0 += bf2f(a.x); s1 += bf2f(a.y); s2 += bf2f(a.z); s3 += bf2f(a.w);
      }
    }
  }
  s0 += __shfl_xor(s0, 16); s1 += __shfl_xor(s1, 16);
  s2 += __shfl_xor(s2, 16); s3 += __shfl_xor(s3, 16);
  s0 += __shfl_xor(s0, 32); s1 += __shfl_xor(s1, 32);
  s2 += __shfl_xor(s2, 32); s3 += __shfl_xor(s3, 32);
  if (g == 0) {
    ushort4 self = *(const ushort4*)&xh[(size_t)wid * IN_F + fl * 4];
    s0 += bf2f(self.x); s1 += bf2f(self.y);
    s2 += bf2f(self.z); s3 += bf2f(self.w);
    ushort4 r;
    r.x = f2bf(s0); r.y = f2bf(s1); r.z = f2bf(s2); r.w = f2bf(s3);
    *(ushort4*)&xa[(size_t)wid * IN_F + fl * 4] = r;
  }
}

// ========== fused MLP (128-row, 512 thr) + riding copy (no W prefetch) ==========
// eaMode=1: ride FULL eattr copy (gsum in d_ws). eaMode=0: ride ei+batch.
__global__ __launch_bounds__(512) void k_mlp(
    const unsigned short* __restrict__ xa,
    const unsigned short* __restrict__ wt1,
    const unsigned short* __restrict__ wt2,
    const unsigned short* __restrict__ wt3,
    const float* __restrict__ b1, const float* __restrict__ b2,
    const float* __restrict__ b3,
    unsigned short* __restrict__ h3,
    const int* __restrict__ batch,
    float* __restrict__ gsum, float* __restrict__ gsumq,
    const int4* __restrict__ ei4, const int4* __restrict__ bat4,
    const float4* __restrict__ ea4,
    float4* __restrict__ o_ei4, float4* __restrict__ o_b4,
    float4* __restrict__ o_ea4, int eaMode) {
  __shared__ unsigned short sh[128 * 128];   // 32 KB
  __shared__ float ssum[H_F], ssq[H_F];
  const int t = threadIdx.x;
  if (blockIdx.x >= MG) {                    // ---- riding copy blocks ----
    int cb = blockIdx.x - MG;
    if (eaMode) {
      for (int i = cb * 512 + t; i < EA_TOT4; i += CPB * 512)
        o_ea4[i] = ea4[i];
    } else {
      for (int i = cb * 512 + t; i < CP_EIB; i += CPB * 512) {
        if (i < CP_EI4) {
          int4 v = ei4[i];
          o_ei4[i] = make_float4((float)v.x, (float)v.y, (float)v.z, (float)v.w);
        } else {
          int j = i - CP_EI4;
          int4 v = bat4[j];
          o_b4[j] = make_float4((float)v.x, (float)v.y, (float)v.z, (float)v.w);
        }
      }
    }
    return;
  }
  const int lane = t & 63;
  const int wv = t >> 6;                     // 0..7
  const int row16 = lane & 15;
  const int kg = lane >> 4;
  const long blk0 = (long)blockIdx.x * 128;
  const int lr0 = (wv & 3) * 32;
  const int nb = (wv >> 2) * 4;
  f32x4 acc0[4], acc1[4];

  // ---------- stage 1: K=64 from global xa, W1 ----------
  {
    long arow0 = blk0 + lr0 + row16;      if (arow0 > N_NODES - 1) arow0 = N_NODES - 1;
    long arow1 = blk0 + lr0 + 16 + row16; if (arow1 > N_NODES - 1) arow1 = N_NODES - 1;
    bf16x8 a0[2], a1[2];
    const unsigned short* ap0 = xa + arow0 * IN_F + kg * 8;
    const unsigned short* ap1 = xa + arow1 * IN_F + kg * 8;
#pragma unroll
    for (int s = 0; s < 2; ++s) {
      a0[s] = *(const bf16x8*)(ap0 + s * 32);
      a1[s] = *(const bf16x8*)(ap1 + s * 32);
    }
#pragma unroll
    for (int n = 0; n < 4; ++n) {
      acc0[n] = (f32x4){0.f, 0.f, 0.f, 0.f};
      acc1[n] = (f32x4){0.f, 0.f, 0.f, 0.f};
    }
#pragma unroll
    for (int n = 0; n < 4; ++n) {
      const unsigned short* wpn =
          wt1 + (size_t)((nb + n) * 16 + row16) * IN_F + kg * 8;
      bf16x8 b[2];
      b[0] = *(const bf16x8*)(wpn);
      b[1] = *(const bf16x8*)(wpn + 32);
      acc0[n] = __builtin_amdgcn_mfma_f32_16x16x32_bf16(a0[0], b[0], acc0[n], 0, 0, 0);
      acc0[n] = __builtin_amdgcn_mfma_f32_16x16x32_bf16(a0[1], b[1], acc0[n], 0, 0, 0);
      acc1[n] = __builtin_amdgcn_mfma_f32_16x16x32_bf16(a1[0], b[0], acc1[n], 0, 0, 0);
      acc1[n] = __builtin_amdgcn_mfma_f32_16x16x32_bf16(a1[1], b[1], acc1[n], 0, 0, 0);
    }
#pragma unroll
    for (int n = 0; n < 4; ++n) {
      int col = (nb + n) * 16 + row16;
      float bv = b1[col];
#pragma unroll
      for (int r = 0; r < 4; ++r) {
        int lrow0 = lr0 + kg * 4 + r;
        int lrow1 = lrow0 + 16;
        sh[lrow0 * 128 + (col ^ ((lrow0 & 7) << 3))] = f2bf(fmaxf(acc0[n][r] + bv, 0.f));
        sh[lrow1 * 128 + (col ^ ((lrow1 & 7) << 3))] = f2bf(fmaxf(acc1[n][r] + bv, 0.f));
      }
    }
  }
  __syncthreads();

  // ---------- stage 2: K=128 from LDS, W2 -> LDS ----------
  {
    const int lA0 = lr0 + row16, lA1 = lr0 + 16 + row16;
    bf16x8 a0[4], a1[4];
#pragma unroll
    for (int s = 0; s < 4; ++s) {
      int K0 = s * 32 + kg * 8;
      a0[s] = *(const bf16x8*)&sh[lA0 * 128 + (K0 ^ ((lA0 & 7) << 3))];
      a1[s] = *(const bf16x8*)&sh[lA1 * 128 + (K0 ^ ((lA1 & 7) << 3))];
    }
#pragma unroll
    for (int n = 0; n < 4; ++n) {
      acc0[n] = (f32x4){0.f, 0.f, 0.f, 0.f};
      acc1[n] = (f32x4){0.f, 0.f, 0.f, 0.f};
    }
#pragma unroll
    for (int n = 0; n < 4; ++n) {
      const unsigned short* wpn =
          wt2 + (size_t)((nb + n) * 16 + row16) * H_F + kg * 8;
      bf16x8 b[4];
#pragma unroll
      for (int s = 0; s < 4; ++s) b[s] = *(const bf16x8*)(wpn + s * 32);
#pragma unroll
      for (int s = 0; s < 4; ++s) {
        acc0[n] = __builtin_amdgcn_mfma_f32_16x16x32_bf16(a0[s], b[s], acc0[n], 0, 0, 0);
        acc1[n] = __builtin_amdgcn_mfma_f32_16x16x32_bf16(a1[s], b[s], acc1[n], 0, 0, 0);
      }
    }
    __syncthreads();
#pragma unroll
    for (int n = 0; n < 4; ++n) {
      int col = (nb + n) * 16 + row16;
      float bv = b2[col];
#pragma unroll
      for (int r = 0; r < 4; ++r) {
        int lrow0 = lr0 + kg * 4 + r;
        int lrow1 = lrow0 + 16;
        sh[lrow0 * 128 + (col ^ ((lrow0 & 7) << 3))] = f2bf(fmaxf(acc0[n][r] + bv, 0.f));
        sh[lrow1 * 128 + (col ^ ((lrow1 & 7) << 3))] = f2bf(fmaxf(acc1[n][r] + bv, 0.f));
      }
    }
  }
  __syncthreads();

  // ---------- stage 3: K=128 from LDS, W3 -> global h3 + stats ----------
  {
    const int lA0 = lr0 + row16, lA1 = lr0 + 16 + row16;
    bf16x8 a0[4], a1[4];
#pragma unroll
    for (int s = 0; s < 4; ++s) {
      int K0 = s * 32 + kg * 8;
      a0[s] = *(const bf16x8*)&sh[lA0 * 128 + (K0 ^ ((lA0 & 7) << 3))];
      a1[s] = *(const bf16x8*)&sh[lA1 * 128 + (K0 ^ ((lA1 & 7) << 3))];
    }
#pragma unroll
    for (int n = 0; n < 4; ++n) {
      acc0[n] = (f32x4){0.f, 0.f, 0.f, 0.f};
      acc1[n] = (f32x4){0.f, 0.f, 0.f, 0.f};
    }
#pragma unroll
    for (int n = 0; n < 4; ++n) {
      const unsigned short* wpn =
          wt3 + (size_t)((nb + n) * 16 + row16) * H_F + kg * 8;
      bf16x8 b[4];
#pragma unroll
      for (int s = 0; s < 4; ++s) b[s] = *(const bf16x8*)(wpn + s * 32);
#pragma unroll
      for (int s = 0; s < 4; ++s) {
        acc0[n] = __builtin_amdgcn_mfma_f32_16x16x32_bf16(a0[s], b[s], acc0[n], 0, 0, 0);
        acc1[n] = __builtin_amdgcn_mfma_f32_16x16x32_bf16(a1[s], b[s], acc1[n], 0, 0, 0);
      }
    }
#pragma unroll
    for (int n = 0; n < 4; ++n) {
      int col = (nb + n) * 16 + row16;
      float bv = b3[col];
#pragma unroll
      for (int r = 0; r < 4; ++r) {
        long row0 = blk0 + lr0 + kg * 4 + r;
        long row1 = row0 + 16;
        if (row0 < N_NODES)
          h3[row0 * H_F + col] = f2bf(fmaxf(acc0[n][r] + bv, 0.f));
        if (row1 < N_NODES)
          h3[row1 * H_F + col] = f2bf(fmaxf(acc1[n][r] + bv, 0.f));
      }
    }
    long lastrow = blk0 + 127; if (lastrow > N_NODES - 1) lastrow = N_NODES - 1;
    const int glo = batch[blk0];
    const int ghi = batch[lastrow];
    int br0[4], br1[4];
#pragma unroll
    for (int r = 0; r < 4; ++r) {
      long row0 = blk0 + lr0 + kg * 4 + r;
      long row1 = row0 + 16;
      br0[r] = (row0 < N_NODES) ? batch[row0] : -1;
      br1[r] = (row1 < N_NODES) ? batch[row1] : -1;
    }
    for (int g = glo; g <= ghi; ++g) {
      if (t < H_F) { ssum[t] = 0.f; ssq[t] = 0.f; }
      __syncthreads();
#pragma unroll
      for (int n = 0; n < 4; ++n) {
        int col = (nb + n) * 16 + row16;
        float bvn = b3[col];
        float sn = 0.f, qn = 0.f;
#pragma unroll
        for (int r = 0; r < 4; ++r) {
          if (br0[r] == g) { float f = fmaxf(acc0[n][r] + bvn, 0.f); sn += f; qn += f * f; }
          if (br1[r] == g) { float f = fmaxf(acc1[n][r] + bvn, 0.f); sn += f; qn += f * f; }
        }
        sn += __shfl_xor(sn, 16); qn += __shfl_xor(qn, 16);
        sn += __shfl_xor(sn, 32); qn += __shfl_xor(qn, 32);
        if (kg == 0) {
          atomicAdd(&ssum[col], sn);
          atomicAdd(&ssq[col], qn);
        }
      }
      __syncthreads();
      if (t < H_F) {
        unsafeAtomicAdd(&gsum[(size_t)g * H_F + t], ssum[t]);
        unsafeAtomicAdd(&gsumq[(size_t)g * H_F + t], ssq[t]);
      }
      __syncthreads();
    }
  }
}

// ---- apply2: inline finalize; h3 bf16 -> hemb fp32 + flat segment max ----
__global__ __launch_bounds__(256) void k_apply2(
    const unsigned short* __restrict__ h3, const int* __restrict__ batch,
    const float* __restrict__ gsum, const float* __restrict__ gsumsq,
    const float* __restrict__ gms, const float* __restrict__ gw,
    const float* __restrict__ gb, float* __restrict__ hemb,
    float* __restrict__ flat) {
  const int t = threadIdx.x;
  const int rg = t >> 5, fq = t & 31;
  const int m0 = blockIdx.x * 32;
  const int r0 = m0 + rg * 4;
  const int c0 = fq * 4;
  const float4 bb = *(const float4*)&gb[c0];
  const float4 gm = *(const float4*)&gms[c0];
  const float4 gwv = *(const float4*)&gw[c0];
  const int glo = batch[m0], ghi = batch[m0 + 31];
  __shared__ int sb[2];
  __shared__ __align__(16) float4 mred[8][32];
  if (glo == ghi) {
    if (t < 2) sb[t] = bsearch_batch(batch, glo + t);
    __syncthreads();
    float c = fmaxf((float)(sb[1] - sb[0]), 1.0f);
    float4 S = *(const float4*)&gsum[(size_t)glo * H_F + c0];
    float4 Q = *(const float4*)&gsumsq[(size_t)glo * H_F + c0];
    float4 mm, ss;
    {
      float mean, ms, var;
      mean = S.x / c; ms = mean * gm.x; var = fmaxf(Q.x / c - 2.f * ms * mean + ms * ms, 0.f);
      mm.x = ms; ss.x = gwv.x * rsqrtf(var + GN_EPS);
      mean = S.y / c; ms = mean * gm.y; var = fmaxf(Q.y / c - 2.f * ms * mean + ms * ms, 0.f);
      mm.y = ms; ss.y = gwv.y * rsqrtf(var + GN_EPS);
      mean = S.z / c; ms = mean * gm.z; var = fmaxf(Q.z / c - 2.f * ms * mean + ms * ms, 0.f);
      mm.z = ms; ss.z = gwv.z * rsqrtf(var + GN_EPS);
      mean = S.w / c; ms = mean * gm.w; var = fmaxf(Q.w / c - 2.f * ms * mean + ms * ms, 0.f);
      mm.w = ms; ss.w = gwv.w * rsqrtf(var + GN_EPS);
    }
    float4 mx = {-INFINITY, -INFINITY, -INFINITY, -INFINITY};
#pragma unroll
    for (int i = 0; i < 4; ++i) {
      size_t idx = (size_t)(r0 + i) * H_F + c0;
      ushort4 u = *(const ushort4*)&h3[idx];
      float4 v;
      v.x = fmaxf((bf2f(u.x) - mm.x) * ss.x + bb.x, 0.f);
      v.y = fmaxf((bf2f(u.y) - mm.y) * ss.y + bb.y, 0.f);
      v.z = fmaxf((bf2f(u.z) - mm.z) * ss.z + bb.z, 0.f);
      v.w = fmaxf((bf2f(u.w) - mm.w) * ss.w + bb.w, 0.f);
      *(float4*)&hemb[idx] = v;
      mx.x = fmaxf(mx.x, v.x); mx.y = fmaxf(mx.y, v.y);
      mx.z = fmaxf(mx.z, v.z); mx.w = fmaxf(mx.w, v.w);
    }
    mred[rg][fq] = mx;
    __syncthreads();
    if (rg == 0) {
#pragma unroll
      for (int j = 1; j < 8; ++j) {
        float4 a = mred[j][fq];
        mx.x = fmaxf(mx.x, a.x); mx.y = fmaxf(mx.y, a.y);
        mx.z = fmaxf(mx.z, a.z); mx.w = fmaxf(mx.w, a.w);
      }
      int* pf = (int*)&flat[(size_t)glo * H_F + c0];
      atomicMax(pf + 0, __float_as_int(mx.x));
      atomicMax(pf + 1, __float_as_int(mx.y));
      atomicMax(pf + 2, __float_as_int(mx.z));
      atomicMax(pf + 3, __float_as_int(mx.w));
    }
  } else {
    int gcur = -1;
    float4 mm = {0,0,0,0}, ss = {0,0,0,0};
    float4 mx = {-INFINITY, -INFINITY, -INFINITY, -INFINITY};
#pragma unroll
    for (int i = 0; i < 4; ++i) {
      int g = batch[r0 + i];
      if (g != gcur) {
        if (gcur >= 0) {
          int* pf = (int*)&flat[(size_t)gcur * H_F + c0];
          atomicMax(pf + 0, __float_as_int(mx.x));
          atomicMax(pf + 1, __float_as_int(mx.y));
          atomicMax(pf + 2, __float_as_int(mx.z));
          atomicMax(pf + 3, __float_as_int(mx.w));
          mx = make_float4(-INFINITY, -INFINITY, -INFINITY, -INFINITY);
        }
        gcur = g;
        int lo = bsearch_batch(batch, g);
        int hi = bsearch_batch(batch, g + 1);
        float c = fmaxf((float)(hi - lo), 1.0f);
        float4 S = *(const float4*)&gsum[(size_t)g * H_F + c0];
        float4 Q = *(const float4*)&gsumsq[(size_t)g * H_F + c0];
        float mean, ms, var;
        mean = S.x / c; ms = mean * gm.x; var = fmaxf(Q.x / c - 2.f * ms * mean + ms * ms, 0.f);
        mm.x = ms; ss.x = gwv.x * rsqrtf(var + GN_EPS);
        mean = S.y / c; ms = mean * gm.y; var = fmaxf(Q.y / c - 2.f * ms * mean + ms * ms, 0.f);
        mm.y = ms; ss.y = gwv.y * rsqrtf(var + GN_EPS);
        mean = S.z / c; ms = mean * gm.z; var = fmaxf(Q.z / c - 2.f * ms * mean + ms * ms, 0.f);
        mm.z = ms; ss.z = gwv.z * rsqrtf(var + GN_EPS);
        mean = S.w / c; ms = mean * gm.w; var = fmaxf(Q.w / c - 2.f * ms * mean + ms * ms, 0.f);
        mm.w = ms; ss.w = gwv.w * rsqrtf(var + GN_EPS);
      }
      size_t idx = (size_t)(r0 + i) * H_F + c0;
      ushort4 u = *(const ushort4*)&h3[idx];
      float4 v;
      v.x = fmaxf((bf2f(u.x) - mm.x) * ss.x + bb.x, 0.f);
      v.y = fmaxf((bf2f(u.y) - mm.y) * ss.y + bb.y, 0.f);
      v.z = fmaxf((bf2f(u.z) - mm.z) * ss.z + bb.z, 0.f);
      v.w = fmaxf((bf2f(u.w) - mm.w) * ss.w + bb.w, 0.f);
      *(float4*)&hemb[idx] = v;
      mx.x = fmaxf(mx.x, v.x); mx.y = fmaxf(mx.y, v.y);
      mx.z = fmaxf(mx.z, v.z); mx.w = fmaxf(mx.w, v.w);
    }
    int* pf = (int*)&flat[(size_t)gcur * H_F + c0];
    atomicMax(pf + 0, __float_as_int(mx.x));
    atomicMax(pf + 1, __float_as_int(mx.y));
    atomicMax(pf + 2, __float_as_int(mx.z));
    atomicMax(pf + 3, __float_as_int(mx.w));
  }
}

// ---- fallback tail copy (small-ws path only) ----
__global__ __launch_bounds__(256) void k_copy_ea(
    const float4* __restrict__ ea4, float4* __restrict__ o_ea4, int n4) {
  int i = blockIdx.x * 256 + threadIdx.x;
  if (i < n4) o_ea4[i] = ea4[i];
}

extern "C" void kernel_launch(void* const* d_in, const int* in_sizes, int n_in,
                              void* d_out, int out_size, void* d_ws, size_t ws_size,
                              hipStream_t stream) {
  const float* inputs = (const float*)d_in[0];
  const int*   ei     = (const int*)d_in[1];
  const int*   batch  = (const int*)d_in[2];
  const float* eattr  = (const float*)d_in[3];
  const float* W1 = (const float*)d_in[4];
  const float* b1 = (const float*)d_in[5];
  const float* W2 = (const float*)d_in[6];
  const float* b2 = (const float*)d_in[7];
  const float* W3 = (const float*)d_in[8];
  const float* b3 = (const float*)d_in[9];
  const float* gw  = (const float*)d_in[10];
  const float* gb  = (const float*)d_in[11];
  const float* gms = (const float*)d_in[12];

  float* out = (float*)d_out;
  float* hemb  = out;
  float* flat  = out + 12800000;
  float* o_ei  = out + 12832768;
  float* o_ea  = out + 16032768;
  float* o_b   = out + 28832768;

  unsigned int*   binBuf  = (unsigned int*)hemb;
  unsigned int*   binBuf2 = (unsigned int*)(hemb + 2100000);
  unsigned short* xh = (unsigned short*)(hemb + 4200000);
  unsigned short* xa = (unsigned short*)(hemb + 7600000);
  int*            csr = (int*)o_ea;

  const bool big = ws_size >= (size_t)25944064;
  unsigned short* h3;
  float *gsum, *gsumq;
  unsigned short *wt;
  int *cnt, *ovfc, *gbc, *gbc2, *ovf;
  if (big) {
    float* ws = (float*)d_ws;
    h3    = (unsigned short*)d_ws;            // 6.4M floats
    gsum  = ws + 6400000;
    gsumq = ws + 6432768;
    wt    = (unsigned short*)(ws + 6465536);
    cnt   = (int*)o_ea + 3400000;
    ovfc  = (int*)o_ea + 3500000;
  } else {
    h3    = (unsigned short*)(o_ea + 6400000);
    gsum  = o_ea + 3200000;
    gsumq = o_ea + 3232768;
    wt    = (unsigned short*)(o_ea + 3265536);
    cnt   = (int*)o_ei;
    ovfc  = (int*)o_ei + 100000;
  }
  gbc  = ovfc + 8;
  gbc2 = ovfc + 16;
  ovf  = ovfc + 160;
  unsigned short* wt1 = wt;
  unsigned short* wt2 = wt + 8192;
  unsigned short* wt3 = wt + 24576;

  hipMemsetAsync(ovfc, 0, 160 * sizeof(int), stream);   // ovfc+gbc+gbc2
  const int prepBlocks = (PREP_FL + 255) / 256;         // 6506
  k_binprep<<<BINB + prepBlocks, 256, 0, stream>>>(
      ei, ei + N_EDGES, binBuf, gbc, (const float4*)inputs, W1, W2, W3,
      (ushort4*)xh, (float4*)gsum, wt, (float4*)flat);
  k_bin2<<<256, 256, 0, stream>>>(binBuf, gbc, binBuf2, gbc2);
  k_fill5<<<NBINS * NSUB, 256, 0, stream>>>(binBuf2, gbc2, csr, cnt, ovfc, ovf);
  if (big) {
    k_gather<<<GCB + GCPB, 256, 0, stream>>>(xh, csr, cnt, xa, ovfc, ovf,
        (const int4*)ei, (const int4*)batch, (float4*)o_ei, (float4*)o_b);
    k_mlp<<<MG + CPB, 512, 0, stream>>>(xa, wt1, wt2, wt3, b1, b2, b3, h3, batch,
        gsum, gsumq, (const int4*)ei, (const int4*)batch, (const float4*)eattr,
        (float4*)o_ei, (float4*)o_b, (float4*)o_ea, 1);
    k_apply2<<<N_NODES / 32, 256, 0, stream>>>(h3, batch, gsum, gsumq, gms, gw, gb,
                                               hemb, flat);
  } else {
    k_gather<<<GCB, 256, 0, stream>>>(xh, csr, cnt, xa, ovfc, ovf,
        (const int4*)ei, (const int4*)batch, (float4*)o_ei, (float4*)o_b);
    k_mlp<<<MG + CPB, 512, 0, stream>>>(xa, wt1, wt2, wt3, b1, b2, b3, h3, batch,
        gsum, gsumq, (const int4*)ei, (const int4*)batch, (const float4*)eattr,
        (float4*)o_ei, (float4*)o_b, (float4*)o_ea, 0);
    k_apply2<<<N_NODES / 32, 256, 0, stream>>>(h3, batch, gsum, gsumq, gms, gw, gb,
                                               hemb, flat);
    k_copy_ea<<<(N_EDGES * 2 + 255) / 256, 256, 0, stream>>>(
        (const float4*)eattr, (float4*)o_ea, N_EDGES * 2);
  }
}